// Round 1
// baseline (255.904 us; speedup 1.0000x reference)
//
#include <hip/hip_runtime.h>
#include <hip/hip_bf16.h>

#define BB 8
#define CC 256
#define NN 4096
#define KP 64   // projection dim K = C/4
#define LOG2E 1.44269504088896f

typedef _Float16 f16x8 __attribute__((ext_vector_type(8)));
typedef _Float16 f16x4 __attribute__((ext_vector_type(4)));
typedef float    f32x4 __attribute__((ext_vector_type(4)));

#define MFMA16(a, b, c) __builtin_amdgcn_mfma_f32_16x16x32_f16((a), (b), (c), 0, 0, 0)

// exp2 (g is pre-scaled by log2e in proj, so softmax runs in base-2)
__device__ __forceinline__ float fast_exp2(float x) {
#if __has_builtin(__builtin_amdgcn_exp2f)
    return __builtin_amdgcn_exp2f(x);
#else
    return __expf(x * 0.69314718055994531f);
#endif
}

// 16-lane (DPP-row) rotate reductions: VALU-speed, off the LDS pipe
template<int CTRL>
__device__ __forceinline__ float dpp_ror_f(float x) {
    return __int_as_float(__builtin_amdgcn_update_dpp(
        0, __float_as_int(x), CTRL, 0xF, 0xF, true));
}
__device__ __forceinline__ float max16(float x) {
    x = fmaxf(x, dpp_ror_f<0x128>(x));
    x = fmaxf(x, dpp_ror_f<0x124>(x));
    x = fmaxf(x, dpp_ror_f<0x122>(x));
    x = fmaxf(x, dpp_ror_f<0x121>(x));
    return x;
}
__device__ __forceinline__ float sum16(float x) {
    x += dpp_ror_f<0x128>(x);
    x += dpp_ror_f<0x124>(x);
    x += dpp_ror_f<0x122>(x);
    x += dpp_ror_f<0x121>(x);
    return x;
}

// ---------------------------------------------------------------------------
// Kernel 0: WF|WG|WH fp32 -> concatenated fp16 W16[384][256].
// ---------------------------------------------------------------------------
__global__ __launch_bounds__(256) void wconv_kernel(
    const float* __restrict__ WF, const float* __restrict__ WG,
    const float* __restrict__ WH, _Float16* __restrict__ W16)
{
    int gid = blockIdx.x * 256 + threadIdx.x;
    int i4  = gid * 4;
    const float* src;
    if (i4 < 64 * CC)        src = WF + i4;
    else if (i4 < 128 * CC)  src = WG + (i4 - 64 * CC);
    else                     src = WH + (i4 - 128 * CC);
    float4 v = *(const float4*)src;
    f16x4 o = { (_Float16)v.x, (_Float16)v.y, (_Float16)v.z, (_Float16)v.w };
    *(f16x4*)(W16 + i4) = o;
}

// ---------------------------------------------------------------------------
// Kernel 1: fp16 MFMA projection, 64-token tiles.
// D[384 out][64 tok] = W16 x feat. Wave w owns out-rows [w*96, w*96+96).
// g rows are pre-scaled by log2e (softmax invariant; lets attn use raw exp2).
// ---------------------------------------------------------------------------
__global__ __launch_bounds__(256, 3) void proj16_kernel(
    const float* __restrict__ feat, const _Float16* __restrict__ W16,
    _Float16* __restrict__ fb, _Float16* __restrict__ gb,
    _Float16* __restrict__ hT)
{
    __shared__ __align__(16) _Float16 ft[64][264];
    const int b = blockIdx.y, n0 = blockIdx.x * 64, t = threadIdx.x;

    // stage feat[b][:, n0..n0+63] -> ft[tok][c] fp16 (transpose + convert)
    #pragma unroll
    for (int i = 0; i < 16; i++) {
        int v = t + i * 256, c = v >> 4, nq = v & 15;
        float4 x = *(const float4*)(feat + ((size_t)b * CC + c) * NN + n0 + nq * 4);
        ft[nq * 4 + 0][c] = (_Float16)x.x;
        ft[nq * 4 + 1][c] = (_Float16)x.y;
        ft[nq * 4 + 2][c] = (_Float16)x.z;
        ft[nq * 4 + 3][c] = (_Float16)x.w;
    }
    __syncthreads();

    const int w = t >> 6, lane = t & 63, quad = lane >> 4, ln = lane & 15;
    const int rowbase = w * 96;

    f32x4 acc[6][4] = {};
    #pragma unroll
    for (int ks = 0; ks < 8; ks++) {
        const int c0 = ks * 32;
        f16x8 bfr[4];
        #pragma unroll
        for (int tf = 0; tf < 4; tf++)
            bfr[tf] = *(const f16x8*)&ft[tf * 16 + ln][c0 + quad * 8];
        #pragma unroll
        for (int af = 0; af < 6; af++) {
            f16x8 a = *(const f16x8*)(W16 + (size_t)(rowbase + af * 16 + ln) * CC + c0 + quad * 8);
            #pragma unroll
            for (int tf = 0; tf < 4; tf++)
                acc[af][tf] = MFMA16(a, bfr[tf], acc[af][tf]);
        }
    }

    // C/D layout: col(tok)=ln, row(out)=quad*4+r
    #pragma unroll
    for (int af = 0; af < 6; af++) {
        const int orow0 = rowbase + af * 16 + quad * 4;   // wave-uniform range
        if (orow0 < 64) {
            #pragma unroll
            for (int tf = 0; tf < 4; tf++) {
                const int tok = n0 + tf * 16 + ln;
                f16x4 pk = { (_Float16)acc[af][tf][0], (_Float16)acc[af][tf][1],
                             (_Float16)acc[af][tf][2], (_Float16)acc[af][tf][3] };
                *(f16x4*)(fb + ((size_t)b * NN + tok) * KP + orow0) = pk;
            }
        } else if (orow0 < 128) {
            #pragma unroll
            for (int tf = 0; tf < 4; tf++) {
                const int tok = n0 + tf * 16 + ln;
                f16x4 pk = { (_Float16)(acc[af][tf][0] * LOG2E),
                             (_Float16)(acc[af][tf][1] * LOG2E),
                             (_Float16)(acc[af][tf][2] * LOG2E),
                             (_Float16)(acc[af][tf][3] * LOG2E) };
                *(f16x4*)(gb + ((size_t)b * NN + tok) * KP + (orow0 - 64)) = pk;
            }
        } else {
            #pragma unroll
            for (int r = 0; r < 4; r++) {
                const int d = orow0 - 128 + r;
                f16x4 pk = { (_Float16)acc[af][0][r], (_Float16)acc[af][1][r],
                             (_Float16)acc[af][2][r], (_Float16)acc[af][3][r] };
                *(f16x4*)(hT + ((size_t)b * CC + d) * NN + n0 + ln * 4) = pk;
            }
        }
    }
}

// ---------------------------------------------------------------------------
// Kernel 2: fp16 MFMA flash attention, Tq=64, Tm=64, 4 symmetric waves.
// Deferred-max online softmax (THR=10 base-2 units): the running max m_run is
// only raised when a row's tile-max exceeds m_run+THR (p <= 2^10, safe in
// fp16; common scale cancels in o/l). Common path skips max16 DPP reduce,
// alpha exp2/stores, AND the cross-wave acc-rescale (gated by per-wave LDS
// change flags, read as wave-uniform broadcasts -> uniform branch per qf).
// l_run keeps per-lane PARTIAL sums; the 16-lane sum16 reduce runs once after
// the loop (linearity), not per iteration.
// Prefetches (next f-tile, this hv-tile) issued AFTER barrier 1 so the
// vmcnt(0)-before-barrier drain lands at barrier 2 with QK^T+softmax as cover.
// ---------------------------------------------------------------------------
__global__ __launch_bounds__(256, 2) void attn16_kernel(
    const _Float16* __restrict__ fb, const _Float16* __restrict__ gb,
    const _Float16* __restrict__ hT, const float* __restrict__ inp,
    const float* __restrict__ gamma, float* __restrict__ out)
{
    __shared__ __align__(16) _Float16 g_s[64][72];
    __shared__ __align__(16) _Float16 f_s[64][72];
    __shared__ __align__(16) _Float16 p_s[64][72];
    __shared__ float alpha_s[64];
    __shared__ float l_s[64];
    __shared__ float chg_s[4];

    const int b = blockIdx.x, q0 = blockIdx.y * 64, t = threadIdx.x;
    const int w = t >> 6, lane = t & 63, quad = lane >> 4, ln = lane & 15;
    const int row = t >> 2, kq = t & 3;
    const int dbase = w * 64;

    // stage g tile [64 q][64 k] once (already log2e-scaled by proj)
    {
        const _Float16* src = gb + ((size_t)b * NN + q0 + row) * KP + kq * 16;
        *(f16x8*)&g_s[row][kq * 16]     = *(const f16x8*)(src);
        *(f16x8*)&g_s[row][kq * 16 + 8] = *(const f16x8*)(src + 8);
    }
    // preload f tile 0 into registers
    f16x8 fr0, fr1;
    {
        const _Float16* src = fb + ((size_t)b * NN + row) * KP + kq * 16;
        fr0 = *(const f16x8*)(src);
        fr1 = *(const f16x8*)(src + 8);
    }
    __syncthreads();   // g_s visible

    // hoist loop-invariant A-fragments of QK^T
    f16x8 ag[2];
    ag[0] = *(const f16x8*)&g_s[w * 16 + ln][quad * 8];
    ag[1] = *(const f16x8*)&g_s[w * 16 + ln][32 + quad * 8];

    float m_run[4] = {-1e30f, -1e30f, -1e30f, -1e30f};
    float l_run[4] = {0.f, 0.f, 0.f, 0.f};   // per-lane PARTIAL row sums
    f32x4 acc[4][4] = {};
    f16x8 hv[2][4];

    #pragma unroll 1
    for (int mt = 0; mt < NN / 64; mt++) {
        const int m0 = mt * 64;

        // current f tile regs -> LDS
        *(f16x8*)&f_s[row][kq * 16]     = fr0;
        *(f16x8*)&f_s[row][kq * 16 + 8] = fr1;
        __syncthreads();   // barrier 1: f_s ready

        // issue prefetches NOW: they drain at barrier 2, covered by QK+softmax
        {
            const int m0n = ((mt + 1) & 63) * 64;   // wrap: harmless reload
            const _Float16* srcf = fb + ((size_t)b * NN + m0n + row) * KP + kq * 16;
            fr0 = *(const f16x8*)(srcf);
            fr1 = *(const f16x8*)(srcf + 8);
            #pragma unroll
            for (int ks = 0; ks < 2; ks++)
                #pragma unroll
                for (int df = 0; df < 4; df++)
                    hv[ks][df] = *(const f16x8*)(hT +
                        ((size_t)b * CC + dbase + df * 16 + ln) * NN + m0 + ks * 32 + quad * 8);
        }

        // ---- QK^T for this wave's q-stripe ----
        f32x4 S[4] = {};
        #pragma unroll
        for (int ks = 0; ks < 2; ks++) {
            #pragma unroll
            for (int mf = 0; mf < 4; mf++) {
                f16x8 bf = *(const f16x8*)&f_s[mf * 16 + ln][ks * 32 + quad * 8];
                S[mf] = MFMA16(ag[ks], bf, S[mf]);
            }
        }

        // ---- deferred-max online softmax (base-2), rows q = w*16+quad*4+r --
        float pmax[4];
        bool upd = false;
        #pragma unroll
        for (int r = 0; r < 4; r++) {
            pmax[r] = fmaxf(fmaxf(S[0][r], S[1][r]), fmaxf(S[2][r], S[3][r]));
            upd |= (pmax[r] > m_run[r] + 10.0f);
        }
        const bool wave_upd = (__ballot(upd) != 0ull);   // wave-uniform
        if (wave_upd) {
            // rare path: tighten max for all 4 rows, publish alphas
            #pragma unroll
            for (int r = 0; r < 4; r++) {
                float mx   = max16(pmax[r]);
                float mnew = fmaxf(m_run[r], mx);
                float al   = fast_exp2(m_run[r] - mnew);
                l_run[r] *= al;
                m_run[r]  = mnew;
                if (ln == 0) alpha_s[w * 16 + quad * 4 + r] = al;
            }
        }
        if (lane == 0) chg_s[w] = wave_upd ? 1.0f : 0.0f;
        #pragma unroll
        for (int r = 0; r < 4; r++) {
            float p0 = fast_exp2(S[0][r] - m_run[r]);
            float p1 = fast_exp2(S[1][r] - m_run[r]);
            float p2 = fast_exp2(S[2][r] - m_run[r]);
            float p3 = fast_exp2(S[3][r] - m_run[r]);
            l_run[r] += (p0 + p1) + (p2 + p3);   // per-lane partial, reduced at end
            f16x4 pk = { (_Float16)p0, (_Float16)p1, (_Float16)p2, (_Float16)p3 };
            *(f16x4*)&p_s[w * 16 + quad * 4 + r][ln * 4] = pk;   // permuted col m' = ln*4 + mf
        }
        __syncthreads();   // barrier 2: p_s/chg_s/alpha_s visible (+ prefetch drain)

        // ---- rescale, gated per wave-of-origin (wave-uniform branches) ----
        {
            float c0 = chg_s[0], c1 = chg_s[1], c2 = chg_s[2], c3 = chg_s[3];
            float chg[4] = {c0, c1, c2, c3};
            #pragma unroll
            for (int qf = 0; qf < 4; qf++) {
                if (chg[qf] != 0.0f) {
                    #pragma unroll
                    for (int r = 0; r < 4; r++) {
                        float al = alpha_s[qf * 16 + quad * 4 + r];
                        #pragma unroll
                        for (int df = 0; df < 4; df++)
                            acc[qf][df][r] *= al;
                    }
                }
            }
        }

        // ---- PV: P x h^T over this wave's 64 channels ----
        #pragma unroll
        for (int ks = 0; ks < 2; ks++) {
            #pragma unroll
            for (int qf = 0; qf < 4; qf++) {
                f16x8 ap = *(const f16x8*)&p_s[qf * 16 + ln][ks * 32 + quad * 8];
                #pragma unroll
                for (int df = 0; df < 4; df++)
                    acc[qf][df] = MFMA16(ap, hv[ks][df], acc[qf][df]);
            }
        }
    }

    // ---- finish l (deferred 16-lane reduce), exchange across waves ----
    #pragma unroll
    for (int r = 0; r < 4; r++) {
        float lt = sum16(l_run[r]);
        if (ln == 0) l_s[w * 16 + quad * 4 + r] = lt;
    }
    __syncthreads();

    const float gam = gamma[0];
    #pragma unroll
    for (int qf = 0; qf < 4; qf++) {
        #pragma unroll
        for (int r = 0; r < 4; r++) {
            const int q = qf * 16 + quad * 4 + r;
            const float linv = 1.0f / l_s[q];
            #pragma unroll
            for (int df = 0; df < 4; df++) {
                const int d = dbase + df * 16 + ln;
                size_t idx = ((size_t)b * NN + q0 + q) * CC + d;
                out[idx] = fmaf(gam, acc[qf][df][r] * linv, inp[idx]);
            }
        }
    }
}

// ---------------------------------------------------------------------------
extern "C" void kernel_launch(void* const* d_in, const int* in_sizes, int n_in,
                              void* d_out, int out_size, void* d_ws, size_t ws_size,
                              hipStream_t stream) {
    const float* input = (const float*)d_in[0];
    const float* nms   = (const float*)d_in[1];
    const float* WF    = (const float*)d_in[2];
    const float* WG    = (const float*)d_in[3];
    const float* WH    = (const float*)d_in[4];
    const float* gamma = (const float*)d_in[5];
    float* out = (float*)d_out;

    // workspace: W16 (192 KB) | fb16 (4 MB) | gb16 (4 MB) | hT16 (16 MB)
    char* ws = (char*)d_ws;
    _Float16* W16  = (_Float16*)ws;
    _Float16* fb16 = (_Float16*)(ws + 196608);
    _Float16* gb16 = (_Float16*)(ws + 196608 + 4194304);
    _Float16* hT16 = (_Float16*)(ws + 196608 + 2 * 4194304);

    wconv_kernel<<<96, 256, 0, stream>>>(WF, WG, WH, W16);
    proj16_kernel<<<dim3(NN / 64, BB), 256, 0, stream>>>(nms, W16, fb16, gb16, hT16);
    attn16_kernel<<<dim3(BB, NN / 64), 256, 0, stream>>>(fb16, gb16, hT16, input, gamma, out);
}